// Round 10
// baseline (1291.157 us; speedup 1.0000x reference)
//
#include <hip/hip_runtime.h>

// GRU B=256,T=2000,I=23,H=128 (gate order r,z,n) + mean over T.
// 1 batch row per block, 256 blocks (1/CU). v13: 1024 threads = 16 waves,
// 4 waves/SIMD.
//
// v13 vs v11: halve per-lane state so it FITS the allocator's observed
// ~84 arch-VGPR ceiling (v11 parked ~60 v2f of weights in AGPRs and paid
// ~114 v_accvgpr_read per step -- the measured 2x instruction surplus).
//   lane bits {0,1,3} = kt in [0,8): k range [16kt,16kt+16)
//   lane bits {2,4,5} = jj in [0,8): row j = wid*8 + jj
//   fold over kt = xor1 + xor2 (quad_perm DPP) + xor8 (row_ror:8 DPP):
//   ALL DPP, no DS hops (bit 2 skipped: xor4 has no DPP form).
//   Weights/lane: 3 gates x 16k = 24 v2f + 6 v2f x-side + 4 biases ~= 77
//   persistent floats -> no AGPR parking, no copy tax.
//   4 waves/SIMD hide the fold+transcendental tail that 2 could not.
// x loads: ONE dwordx4 per step via clamped window e0=min(3kt,19) with
//   zero-masked weights (covers 23 elems across 8 kt-lanes, never OOB).
// h LDS [2][8][20] pad-20: read bank map {0,20,8,28,16,4,24,12}+4m --
//   pairwise disjoint 4-bank spans, zero conflicts, 8-way broadcast.
// Keeps: LDS-only barrier, parity depth-2 x prefetch, exp2 prescale,
// packed v_pk_fma_f32 MACs, lane-local epilogue.

#define Bb 256
#define Tt 2000
#define Ii 23
#define Hh 128

typedef float v2f __attribute__((ext_vector_type(2)));
typedef float v4f __attribute__((ext_vector_type(4)));
typedef float v4fu __attribute__((ext_vector_type(4), aligned(4)));

template <int N> struct ic { static constexpr int v = N; };

template <int ctrl>
__device__ __forceinline__ float dpp_movf(float v) {
    int r = __builtin_amdgcn_update_dpp(0, __builtin_bit_cast(int, v),
                                        ctrl, 0xf, 0xf, true);
    return __builtin_bit_cast(float, r);
}
__device__ __forceinline__ void pk_fma(v2f& a, v2f b, v2f c) {
    asm("v_pk_fma_f32 %0, %1, %2, %0" : "+v"(a) : "v"(b), "v"(c));
}
__device__ __forceinline__ v2f pk_mul(v2f b, v2f c) {
    v2f d;
    asm("v_pk_mul_f32 %0, %1, %2" : "=v"(d) : "v"(b), "v"(c));
    return d;
}
__device__ __forceinline__ float fexp2(float x) {
#if __has_builtin(__builtin_amdgcn_exp2f)
    return __builtin_amdgcn_exp2f(x);
#else
    return exp2f(x);
#endif
}
__device__ __forceinline__ v2f pinv(v2f v) { asm("" : "+v"(v)); return v; }
__device__ __forceinline__ float pinf(float v) { asm("" : "+v"(v)); return v; }
// LDS-only barrier: does NOT drain vmcnt (x prefetch stays in flight).
__device__ __forceinline__ void bar_lds() {
    asm volatile("s_waitcnt lgkmcnt(0)\n\ts_barrier" ::: "memory");
}
// 8-lane fold over lane bits {0,1,3}: xor1+xor2 (quad_perm) + xor8
// (row_ror:8). Pure VALU; every lane of the group ends with the full sum.
__device__ __forceinline__ float ofold(float c) {
    c += dpp_movf<0xB1>(c);    // xor1: quad_perm [1,0,3,2]
    c += dpp_movf<0x4E>(c);    // xor2: quad_perm [2,3,0,1]
    c += dpp_movf<0x128>(c);   // xor8: row_ror:8
    return c;
}

__global__ __launch_bounds__(1024, 4)
void gru_fused(const float* __restrict__ x,     // [B,T,I]
               const float* __restrict__ W_ih,  // [3H,I]
               const float* __restrict__ W_hh,  // [3H,H]
               const float* __restrict__ b_ih,  // [3H]
               const float* __restrict__ b_hh,  // [3H]
               float* __restrict__ out)         // [B,H]
{
    const int b   = blockIdx.x;
    const int tid = threadIdx.x;
    const int wid = tid >> 6;                       // 0..15
    const int l   = tid & 63;
    const int kt  = (l & 3) | ((l & 8) >> 1);       // bits 0,1,3 -> 0..7
    const int jj  = ((l & 4) >> 2) | ((l & 48) >> 3); // bits 2,4,5 -> 0..7
    const int j   = wid * 8 + jj;                   // owned h row
    const int kb  = kt * 16;                        // k range [kb, kb+16)

    // h double buffer: chunk c holds h[16c..16c+16), padded to 20 floats.
    __shared__ __align__(16) float h_db[2][8][20];

    const float L2E = 1.4426950408889634f;   // log2(e)
    const float K2  = 2.0f * L2E;

    // ---- recurrent weights: 8 v2f per gate over k [kb,kb+16) ----
    v2f wr[8], wz[8], wn[8];
    {
        const float* Wr = W_hh + (size_t)j * Hh + kb;
        const float* Wz = W_hh + (size_t)(Hh + j) * Hh + kb;
        const float* Wn = W_hh + (size_t)(2 * Hh + j) * Hh + kb;
        #pragma unroll
        for (int kk = 0; kk < 8; ++kk) {
            v2f a = *reinterpret_cast<const v2f*>(Wr + 2 * kk);
            a[0] *= L2E; a[1] *= L2E; wr[kk] = pinv(a);
            v2f c = *reinterpret_cast<const v2f*>(Wz + 2 * kk);
            c[0] *= L2E; c[1] *= L2E; wz[kk] = pinv(c);
            v2f d = *reinterpret_cast<const v2f*>(Wn + 2 * kk);
            d[0] *= K2;  d[1] *= K2;  wn[kk] = pinv(d);
        }
    }

    // ---- x-side: clamped window e0 = min(3kt,19), elems e0..e0+3 ----
    // kt<7 owns {3kt,3kt+1,3kt+2}: pair0=(w,w), pair1=(w,0)
    // kt=7 owns {21,22}, e0=19:     pair0=(0,0), pair1=(w21,w22)
    const int e0x = (kt < 7) ? 3 * kt : 19;
    const float m0 = (kt < 7) ? 1.0f : 0.0f;   // pair0 mask
    const float m3 = (kt < 7) ? 0.0f : 1.0f;   // pair1.hi mask
    v2f wxr[2], wxz[2], wxn[2];
    {
        const float* Xr = W_ih + (size_t)j * Ii + e0x;
        const float* Xz = W_ih + (size_t)(Hh + j) * Ii + e0x;
        const float* Xn = W_ih + (size_t)(2 * Hh + j) * Ii + e0x;
        v2f t;
        t[0] = Xr[0] * L2E * m0; t[1] = Xr[1] * L2E * m0; wxr[0] = pinv(t);
        t[0] = Xr[2] * L2E;      t[1] = Xr[3] * L2E * m3; wxr[1] = pinv(t);
        t[0] = Xz[0] * L2E * m0; t[1] = Xz[1] * L2E * m0; wxz[0] = pinv(t);
        t[0] = Xz[2] * L2E;      t[1] = Xz[3] * L2E * m3; wxz[1] = pinv(t);
        t[0] = Xn[0] * K2 * m0;  t[1] = Xn[1] * K2 * m0;  wxn[0] = pinv(t);
        t[0] = Xn[2] * K2;       t[1] = Xn[3] * K2 * m3;  wxn[1] = pinv(t);
    }

    // ---- biases (post-fold, per-row, prescaled) ----
    const float br  = pinf((b_ih[j] + b_hh[j]) * L2E);
    const float bz  = pinf((b_ih[Hh + j] + b_hh[Hh + j]) * L2E);
    const float bnh = pinf(b_hh[2 * Hh + j] * K2);
    const float bnx = pinf(b_ih[2 * Hh + j] * K2);

    const float* xptr = x + (size_t)b * Tt * Ii + e0x;  // lane-local x base

    // ---- init ----
    if (tid < Hh) h_db[0][tid >> 4][tid & 15] = 0.0f;
    // depth-2 x prefetch: qA serves even steps, qB odd steps.
    v4f qA = *reinterpret_cast<const v4fu*>(xptr);
    v4f qB = *reinterpret_cast<const v4fu*>(xptr + Ii);
    int xob = 2 * Ii;                  // element offset of row step+2
    float h_prev = 0.0f, acc_mean = 0.0f;
    bar_lds();

    auto body = [&](auto CUR, int s) {
        constexpr int cur = decltype(CUR)::v;
        const int step = s + cur;

        // ---- x-side MACs (register-only, fills DS-latency window) ----
        v2f xp0, xp1;
        if constexpr (cur == 0) {
            xp0[0] = qA[0]; xp0[1] = qA[1]; xp1[0] = qA[2]; xp1[1] = qA[3];
        } else {
            xp0[0] = qB[0]; xp0[1] = qB[1]; xp1[0] = qB[2]; xp1[1] = qB[3];
        }
        v2f ar = pk_mul(wxr[0], xp0); pk_fma(ar, wxr[1], xp1);
        v2f az = pk_mul(wxz[0], xp0); pk_fma(az, wxz[1], xp1);
        v2f ax = pk_mul(wxn[0], xp0); pk_fma(ax, wxn[1], xp1);

        // ---- h-side MACs: 4 b128 broadcast chunks, 6 pk each ----
        v2f ah;
        #pragma unroll
        for (int c = 0; c < 4; ++c) {
            const v4f hc = *reinterpret_cast<const v4f*>(&h_db[cur][kt][4 * c]);
            v2f hpA; hpA[0] = hc[0]; hpA[1] = hc[1];
            v2f hpB; hpB[0] = hc[2]; hpB[1] = hc[3];
            pk_fma(ar, wr[2 * c], hpA); pk_fma(ar, wr[2 * c + 1], hpB);
            pk_fma(az, wz[2 * c], hpA); pk_fma(az, wz[2 * c + 1], hpB);
            if (c == 0) {
                ah = pk_mul(wn[0], hpA); pk_fma(ah, wn[1], hpB);
            } else {
                pk_fma(ah, wn[2 * c], hpA); pk_fma(ah, wn[2 * c + 1], hpB);
            }
        }

        // ---- reload this parity's x for step+2 (stays in flight) ----
        if constexpr (cur == 0) qA = *reinterpret_cast<const v4fu*>(xptr + xob);
        else                    qB = *reinterpret_cast<const v4fu*>(xptr + xob);
        if (step + 3 < Tt) xob += Ii;

        // ---- 8-lane DPP folds + biases: all lanes get full row sums ----
        const float r_s = ofold(ar[0] + ar[1]) + br;
        const float z_s = ofold(az[0] + az[1]) + bz;
        const float ghn = ofold(ah[0] + ah[1]) + bnh;
        const float gxn = ofold(ax[0] + ax[1]) + bnx;

        // ---- lane-local epilogue (uniform across the 8-lane group) ----
        const float r  = __builtin_amdgcn_rcpf(1.0f + fexp2(-r_s));
        const float z  = __builtin_amdgcn_rcpf(1.0f + fexp2(-z_s));
        const float npre = fmaf(r, ghn, gxn);          // scaled by 2*log2e
        const float tt2  = __builtin_amdgcn_rcpf(1.0f + fexp2(-npre));
        const float nn   = fmaf(2.0f, tt2, -1.0f);     // tanh
        const float h_new = fmaf(z, h_prev - nn, nn);
        h_prev = h_new;
        acc_mean += h_new;
        if (kt == 0) h_db[cur ^ 1][j >> 4][j & 15] = h_new;
        bar_lds();   // LDS-only barrier, once per step
    };

    for (int s = 0; s < Tt; s += 2) {
        body(ic<0>{}, s);
        body(ic<1>{}, s);
    }

    if (kt == 0) out[(size_t)b * Hh + j] = acc_mean * (1.0f / Tt);
}

extern "C" void kernel_launch(void* const* d_in, const int* in_sizes, int n_in,
                              void* d_out, int out_size, void* d_ws, size_t ws_size,
                              hipStream_t stream) {
    const float* x    = (const float*)d_in[0];
    const float* W_ih = (const float*)d_in[1];
    const float* W_hh = (const float*)d_in[2];
    const float* b_ih = (const float*)d_in[3];
    const float* b_hh = (const float*)d_in[4];
    float* out = (float*)d_out;

    gru_fused<<<Bb, 1024, 0, stream>>>(x, W_ih, W_hh, b_ih, b_hh, out);
}

// Round 11
// 1029.658 us; speedup vs baseline: 1.2540x; 1.2540x over previous
//
#include <hip/hip_runtime.h>

// GRU B=256,T=2000,I=23,H=128 (gate order r,z,n) + mean over T.
// 1 batch row per block, 256 blocks (1/CU). 512 threads = 8 waves, 2/SIMD.
//
// v14 vs v11 (the 1020us champion; v13's 16-wave variant regressed and is
// reverted): NATIVE PACKED MATH.
// Issue-math forensics: v11 AND v13 both showed the same ~2x VALU
// instruction surplus (v11: ~860cy/SIMD/step issued vs ~440 arithmetic;
// v13: ~1280 vs ~640) across different lane maps and occupancies -- a
// per-MAC constant. Common factor: every MAC was an inline-asm
// v_pk_fma_f32 with a tied "+v" operand. Inline asm defeats the register
// coalescer (1-2 v_mov_b32 marshalling copies per op) and blocks
// scheduling/CSE: ~57 pk asm x ~2 movs == the measured surplus.
// gfx950 has native packed-fp32 codegen: <2 x float> fmul/fma IR selects
// v_pk_mul_f32/v_pk_fma_f32 directly. v14 replaces all pk asm with native
// v2f arithmetic (__builtin_elementwise_fma) -- zero copies, free
// scheduling. Everything else byte-identical to v11:
//   row-per-lane (jj=l>>2 owns row, kt=l&3 k-quarter), DPP-only qfold,
//   lane-local epilogue, LDS-only barrier, depth-2 parity x prefetch,
//   exp2 prescale, [2][4][36] padded h LDS (0 bank conflicts measured).

#define Bb 256
#define Tt 2000
#define Ii 23
#define Hh 128

typedef float v2f __attribute__((ext_vector_type(2)));
typedef float v4f __attribute__((ext_vector_type(4)));

template <int N> struct ic { static constexpr int v = N; };

template <int ctrl>
__device__ __forceinline__ float dpp_movf(float v) {
    int r = __builtin_amdgcn_update_dpp(0, __builtin_bit_cast(int, v),
                                        ctrl, 0xf, 0xf, true);
    return __builtin_bit_cast(float, r);
}
__device__ __forceinline__ float fexp2(float x) {
#if __has_builtin(__builtin_amdgcn_exp2f)
    return __builtin_amdgcn_exp2f(x);
#else
    return exp2f(x);
#endif
}
__device__ __forceinline__ v2f pinv(v2f v) { asm("" : "+v"(v)); return v; }
__device__ __forceinline__ float pinf(float v) { asm("" : "+v"(v)); return v; }
// LDS-only barrier: does NOT drain vmcnt (x prefetch stays in flight).
__device__ __forceinline__ void bar_lds() {
    asm volatile("s_waitcnt lgkmcnt(0)\n\ts_barrier" ::: "memory");
}
// Symmetric quad butterfly: every lane of each quad ends with the quad sum.
// Pure VALU (2x quad_perm DPP + 2 adds) -- no DS pipe involvement.
__device__ __forceinline__ float qfold(float c) {
    c += dpp_movf<0xB1>(c);   // xor1: quad_perm [1,0,3,2]
    c += dpp_movf<0x4E>(c);   // xor2: quad_perm [2,3,0,1]
    return c;
}
// Native packed MACs: LLVM selects v_pk_mul_f32 / v_pk_fma_f32 on gfx950.
__device__ __forceinline__ v2f nfma(v2f a, v2f b, v2f c) {
    return __builtin_elementwise_fma(a, b, c);   // a*b + c
}

__global__ __launch_bounds__(512, 2)
void gru_fused(const float* __restrict__ x,     // [B,T,I]
               const float* __restrict__ W_ih,  // [3H,I]
               const float* __restrict__ W_hh,  // [3H,H]
               const float* __restrict__ b_ih,  // [3H]
               const float* __restrict__ b_hh,  // [3H]
               float* __restrict__ out)         // [B,H]
{
    const int b   = blockIdx.x;
    const int tid = threadIdx.x;
    const int wid = tid >> 6;
    const int l   = tid & 63;
    const int jj  = l >> 2;            // 0..15: row within wave
    const int kt  = l & 3;             // k-quarter
    const int j   = wid * 16 + jj;     // owned h row
    const int kb  = kt * 32;           // k range [kb, kb+32)

    // h double buffer, padded: chunk stride 36 floats (144B, 16B-aligned,
    // banks disjoint across the 4 kt chunks).
    __shared__ __align__(16) float h_db[2][4][36];

    const float L2E = 1.4426950408889634f;   // log2(e)
    const float K2  = 2.0f * L2E;

    // ---- recurrent weights: 16 v2f per gate over k [kb,kb+32) ----
    v2f wr[16], wz[16], wn[16];
    {
        const float* Wr = W_hh + (size_t)j * Hh + kb;
        const float* Wz = W_hh + (size_t)(Hh + j) * Hh + kb;
        const float* Wn = W_hh + (size_t)(2 * Hh + j) * Hh + kb;
        #pragma unroll
        for (int kk = 0; kk < 16; ++kk) {
            v2f a = *reinterpret_cast<const v2f*>(Wr + 2 * kk);
            a[0] *= L2E; a[1] *= L2E; wr[kk] = pinv(a);
            v2f c = *reinterpret_cast<const v2f*>(Wz + 2 * kk);
            c[0] *= L2E; c[1] *= L2E; wz[kk] = pinv(c);
            v2f d = *reinterpret_cast<const v2f*>(Wn + 2 * kk);
            d[0] *= K2;  d[1] *= K2;  wn[kk] = pinv(d);
        }
    }

    // ---- x-side: lane kt covers x[xi0 .. ) as 3 pairs ----
    // kt<3: pairs (xi0,xi0+1),(xi0+2,xi0+3),(xi0+4,xi0+5), xi0=6kt
    // kt=3: pairs (18,19),(20,21),(21,22) with pair2.lo weight = 0
    const int xi0 = (kt < 3) ? kt * 6 : 18;
    const int xo2 = (kt < 3) ? 4 : 3;          // element offset of pair 2
    v2f wxr[3], wxz[3], wxn[3];
    {
        const float* Xr = W_ih + (size_t)j * Ii;
        const float* Xz = W_ih + (size_t)(Hh + j) * Ii;
        const float* Xn = W_ih + (size_t)(2 * Hh + j) * Ii;
        #pragma unroll
        for (int m = 0; m < 3; ++m) {
            const int e0 = xi0 + ((m < 2) ? 2 * m : xo2);
            const float klo = (kt == 3 && m == 2) ? 0.0f : 1.0f;
            v2f a; a[0] = Xr[e0] * L2E * klo; a[1] = Xr[e0 + 1] * L2E;
            wxr[m] = pinv(a);
            v2f c; c[0] = Xz[e0] * L2E * klo; c[1] = Xz[e0 + 1] * L2E;
            wxz[m] = pinv(c);
            v2f d; d[0] = Xn[e0] * K2 * klo;  d[1] = Xn[e0 + 1] * K2;
            wxn[m] = pinv(d);
        }
    }

    // ---- biases (post-fold, per-row, prescaled) ----
    const float br  = pinf((b_ih[j] + b_hh[j]) * L2E);
    const float bz  = pinf((b_ih[Hh + j] + b_hh[Hh + j]) * L2E);
    const float bnh = pinf(b_hh[2 * Hh + j] * K2);
    const float bnx = pinf(b_ih[2 * Hh + j] * K2);

    const float* xrow = x + (size_t)b * Tt * Ii + xi0;  // lane-local x base

    // ---- init ----
    if (tid < Hh) h_db[0][tid >> 5][tid & 31] = 0.0f;
    // depth-2 x prefetch: A serves even steps, B odd steps. 6 scalars each.
    float xA[6], xB[6];
    {
        #pragma unroll
        for (int m = 0; m < 4; ++m) { xA[m] = xrow[m]; xB[m] = xrow[Ii + m]; }
        xA[4] = xrow[xo2];      xA[5] = xrow[xo2 + 1];
        xB[4] = xrow[Ii + xo2]; xB[5] = xrow[Ii + xo2 + 1];
    }
    int xob = 2 * Ii;                  // element offset of row step+2
    float h_prev = 0.0f, acc_mean = 0.0f;
    bar_lds();

    auto body = [&](auto CUR, int s) {
        constexpr int cur = decltype(CUR)::v;
        const int step = s + cur;

        // ---- x-side MACs first (register-only, fills DS-latency window) --
        v2f xp0, xp1, xp2;
        if constexpr (cur == 0) {
            xp0[0]=xA[0]; xp0[1]=xA[1]; xp1[0]=xA[2]; xp1[1]=xA[3];
            xp2[0]=xA[4]; xp2[1]=xA[5];
        } else {
            xp0[0]=xB[0]; xp0[1]=xB[1]; xp1[0]=xB[2]; xp1[1]=xB[3];
            xp2[0]=xB[4]; xp2[1]=xB[5];
        }
        v2f ar = wxr[0] * xp0; ar = nfma(wxr[1], xp1, ar); ar = nfma(wxr[2], xp2, ar);
        v2f az = wxz[0] * xp0; az = nfma(wxz[1], xp1, az); az = nfma(wxz[2], xp2, az);
        v2f ax = wxn[0] * xp0; ax = nfma(wxn[1], xp1, ax); ax = nfma(wxn[2], xp2, ax);

        // ---- h-side MACs: 8 b128 broadcast chunks, 6 pk each ----
        v2f ah;
        #pragma unroll
        for (int c = 0; c < 8; ++c) {
            const v4f hc = *reinterpret_cast<const v4f*>(&h_db[cur][kt][4 * c]);
            v2f hpA; hpA[0] = hc[0]; hpA[1] = hc[1];
            v2f hpB; hpB[0] = hc[2]; hpB[1] = hc[3];
            ar = nfma(wr[2 * c], hpA, ar); ar = nfma(wr[2 * c + 1], hpB, ar);
            az = nfma(wz[2 * c], hpA, az); az = nfma(wz[2 * c + 1], hpB, az);
            if (c == 0) {
                ah = wn[0] * hpA; ah = nfma(wn[1], hpB, ah);
            } else {
                ah = nfma(wn[2 * c], hpA, ah); ah = nfma(wn[2 * c + 1], hpB, ah);
            }
        }

        // ---- reload this parity's x for step+2 (in flight across bars) --
        if constexpr (cur == 0) {
            #pragma unroll
            for (int m = 0; m < 4; ++m) xA[m] = xrow[xob + m];
            xA[4] = xrow[xob + xo2]; xA[5] = xrow[xob + xo2 + 1];
        } else {
            #pragma unroll
            for (int m = 0; m < 4; ++m) xB[m] = xrow[xob + m];
            xB[4] = xrow[xob + xo2]; xB[5] = xrow[xob + xo2 + 1];
        }
        if (step + 3 < Tt) xob += Ii;

        // ---- quad folds (pure DPP) + biases: all 4 lanes get full sums --
        const float r_s = qfold(ar[0] + ar[1]) + br;
        const float z_s = qfold(az[0] + az[1]) + bz;
        const float ghn = qfold(ah[0] + ah[1]) + bnh;
        const float gxn = qfold(ax[0] + ax[1]) + bnx;

        // ---- lane-local epilogue (uniform across the quad) ----
        const float r  = __builtin_amdgcn_rcpf(1.0f + fexp2(-r_s));
        const float z  = __builtin_amdgcn_rcpf(1.0f + fexp2(-z_s));
        const float npre = fmaf(r, ghn, gxn);          // scaled by 2*log2e
        const float tt2  = __builtin_amdgcn_rcpf(1.0f + fexp2(-npre));
        const float nn   = fmaf(2.0f, tt2, -1.0f);     // tanh
        const float h_new = fmaf(z, h_prev - nn, nn);
        h_prev = h_new;
        acc_mean += h_new;
        if (kt == 0) h_db[cur ^ 1][j >> 5][j & 31] = h_new;
        bar_lds();   // LDS-only barrier, once per step
    };

    for (int s = 0; s < Tt; s += 2) {
        body(ic<0>{}, s);
        body(ic<1>{}, s);
    }

    if (kt == 0) out[(size_t)b * Hh + j] = acc_mean * (1.0f / Tt);
}

extern "C" void kernel_launch(void* const* d_in, const int* in_sizes, int n_in,
                              void* d_out, int out_size, void* d_ws, size_t ws_size,
                              hipStream_t stream) {
    const float* x    = (const float*)d_in[0];
    const float* W_ih = (const float*)d_in[1];
    const float* W_hh = (const float*)d_in[2];
    const float* b_ih = (const float*)d_in[3];
    const float* b_hh = (const float*)d_in[4];
    float* out = (float*)d_out;

    gru_fused<<<Bb, 512, 0, stream>>>(x, W_ih, W_hh, b_ih, b_hh, out);
}